// Round 1
// baseline (6061.578 us; speedup 1.0000x reference)
//
#include <hip/hip_runtime.h>
#include <math.h>

#define NSLOPE 0.01f
#define BGRAPH 128
#define PPARTS 8
#define GR 32

__device__ __forceinline__ float lrelu(float v) { return v >= 0.f ? v : NSLOPE * v; }

__global__ void deg_init_kernel(int* __restrict__ deg, int n) {
  int v = blockIdx.x * blockDim.x + threadIdx.x;
  if (v < n) deg[v] = 1;  // self-loop
}

__global__ void deg_count_kernel(const int* __restrict__ dst, int* __restrict__ deg, int ne) {
  int e = blockIdx.x * blockDim.x + threadIdx.x;
  if (e < ne) atomicAdd(&deg[dst[e]], 1);
}

__global__ void dinv_kernel(const int* __restrict__ deg, float* __restrict__ dinv, int n) {
  int v = blockIdx.x * blockDim.x + threadIdx.x;
  if (v < n) dinv[v] = rsqrtf((float)deg[v]);
}

// agg[v] = dinv[v]^2 * x[v]   (self-loop message, doubles as buffer init)
__global__ void self_init_kernel(const float* __restrict__ x, const float* __restrict__ dinv,
                                 float* __restrict__ agg, int n) {
  int tid = blockIdx.x * blockDim.x + threadIdx.x;
  int v = tid >> 5, l = tid & 31;
  if (v >= n) return;
  float di = dinv[v];
  float s = di * di;
  float4 xv = ((const float4*)x)[(size_t)v * 32 + l];
  float4 o;
  o.x = s * xv.x; o.y = s * xv.y; o.z = s * xv.z; o.w = s * xv.w;
  ((float4*)agg)[(size_t)v * 32 + l] = o;
}

// agg[dst] += dinv[src]*dinv[dst] * x[src]; 32 lanes per edge, float4 per lane
__global__ void edge_agg_kernel(const int* __restrict__ src, const int* __restrict__ dst,
                                const float* __restrict__ x, const float* __restrict__ dinv,
                                float* __restrict__ agg, int ne) {
  long tid = (long)blockIdx.x * blockDim.x + threadIdx.x;
  long e = tid >> 5;
  int l = (int)(tid & 31);
  if (e >= ne) return;
  int s = src[e], d = dst[e];
  float norm = dinv[s] * dinv[d];
  float4 xv = ((const float4*)x)[(size_t)s * 32 + l];
  float* ap = agg + (size_t)d * 128 + (size_t)l * 4;
  atomicAdd(ap + 0, norm * xv.x);
  atomicAdd(ap + 1, norm * xv.y);
  atomicAdd(ap + 2, norm * xv.z);
  atomicAdd(ap + 3, norm * xv.w);
}

// In-place: A = lrelu(A @ W + bias). Block=128 threads (thread=col), 32 rows/block.
__global__ __launch_bounds__(128) void gemm_lrelu_kernel(
    float* __restrict__ A, const float* __restrict__ W,
    const float* __restrict__ bias, int n) {
  __shared__ float xs[GR * 128];
  int t = threadIdx.x;
  size_t row0 = (size_t)blockIdx.x * GR;
  if (row0 + GR <= (size_t)n) {
    const float4* A4 = (const float4*)(A + row0 * 128);
    float4* xs4 = (float4*)xs;
#pragma unroll
    for (int i = 0; i < 8; i++) xs4[t + i * 128] = A4[t + i * 128];
  } else {
    for (int idx = t; idx < GR * 128; idx += 128) {
      size_t r = row0 + (size_t)(idx >> 7);
      xs[idx] = (r < (size_t)n) ? A[r * 128 + (idx & 127)] : 0.f;
    }
  }
  __syncthreads();
  float acc[GR];
#pragma unroll
  for (int r = 0; r < GR; r++) acc[r] = 0.f;
  for (int kc = 0; kc < 4; kc++) {
    float w[32];
#pragma unroll
    for (int j = 0; j < 32; j++) w[j] = W[(kc * 32 + j) * 128 + t];
#pragma unroll
    for (int j4 = 0; j4 < 8; j4++) {
#pragma unroll
      for (int r = 0; r < GR; r++) {
        float4 xv = ((const float4*)(xs + r * 128 + kc * 32))[j4];
        acc[r] = fmaf(xv.x, w[j4 * 4 + 0], acc[r]);
        acc[r] = fmaf(xv.y, w[j4 * 4 + 1], acc[r]);
        acc[r] = fmaf(xv.z, w[j4 * 4 + 2], acc[r]);
        acc[r] = fmaf(xv.w, w[j4 * 4 + 3], acc[r]);
      }
    }
  }
  float bv = bias[t];
#pragma unroll
  for (int r = 0; r < GR; r++) {
    size_t row = row0 + r;
    if (row < (size_t)n) A[row * 128 + t] = lrelu(acc[r] + bv);
  }
}

// start[b] = lower_bound(batch, b); batch is sorted. b in [0, nb].
__global__ void bounds_kernel(const int* __restrict__ batch, int* __restrict__ start,
                              int n, int nb) {
  int b = blockIdx.x * blockDim.x + threadIdx.x;
  if (b > nb) return;
  int lo = 0, hi = n;
  while (lo < hi) {
    int mid = (lo + hi) >> 1;
    if (batch[mid] < b) lo = mid + 1; else hi = mid;
  }
  start[b] = lo;
}

__global__ void pool_part_kernel(const float* __restrict__ h, const int* __restrict__ start,
                                 float* __restrict__ part) {
  int b = blockIdx.x / PPARTS, p = blockIdx.x % PPARTS;
  int t = threadIdx.x;
  int s0 = start[b], s1 = start[b + 1];
  int cnt = s1 - s0;
  int per = (cnt + PPARTS - 1) / PPARTS;
  int v0 = s0 + p * per;
  int v1 = min(s1, v0 + per);
  float m = -3.4e38f;
  for (int v = v0; v < v1; v++) m = fmaxf(m, h[(size_t)v * 128 + t]);
  part[(size_t)blockIdx.x * 128 + t] = m;
}

__global__ void pool_combine_kernel(const float* __restrict__ part, float* __restrict__ g) {
  int b = blockIdx.x, t = threadIdx.x;
  float m = -3.4e38f;
#pragma unroll
  for (int p = 0; p < PPARTS; p++) m = fmaxf(m, part[((size_t)b * PPARTS + p) * 128 + t]);
  g[(size_t)b * 128 + t] = m;
}

// Fused head: p1/p2 FC + lrelu -> concat -> fc1 -> fc2 -> out -> sigmoid
__global__ __launch_bounds__(256) void head_kernel(
    const float* __restrict__ g1, const float* __restrict__ g2,
    const float* __restrict__ fcp1W, const float* __restrict__ fcp1b,
    const float* __restrict__ fcp2W, const float* __restrict__ fcp2b,
    const float* __restrict__ fc1W, const float* __restrict__ fc1b,
    const float* __restrict__ fc2W, const float* __restrict__ fc2b,
    const float* __restrict__ outW, const float* __restrict__ outb,
    float* __restrict__ out) {
  __shared__ float grow[256];
  __shared__ float c[256];
  __shared__ float h1[256];
  __shared__ float h2[64];
  int b = blockIdx.x, t = threadIdx.x;
  grow[t] = (t < 128) ? g1[b * 128 + t] : g2[b * 128 + (t - 128)];
  __syncthreads();
  {
    float acc;
    if (t < 128) {
      acc = fcp1b[t];
      for (int k = 0; k < 128; k++) acc = fmaf(grow[k], fcp1W[k * 128 + t], acc);
    } else {
      int tc = t - 128;
      acc = fcp2b[tc];
      for (int k = 0; k < 128; k++) acc = fmaf(grow[128 + k], fcp2W[k * 128 + tc], acc);
    }
    c[t] = lrelu(acc);
  }
  __syncthreads();
  {
    float acc = fc1b[t];
    for (int k = 0; k < 256; k++) acc = fmaf(c[k], fc1W[k * 256 + t], acc);
    h1[t] = lrelu(acc);
  }
  __syncthreads();
  if (t < 64) {
    float acc = fc2b[t];
    for (int k = 0; k < 256; k++) acc = fmaf(h1[k], fc2W[k * 64 + t], acc);
    h2[t] = lrelu(acc);
  }
  __syncthreads();
  if (t < 64) {
    float v = h2[t] * outW[t];
    for (int off = 32; off > 0; off >>= 1) v += __shfl_down(v, off);
    if (t == 0) out[b] = 1.f / (1.f + expf(-(v + outb[0])));
  }
}

extern "C" void kernel_launch(void* const* d_in, const int* in_sizes, int n_in,
                              void* d_out, int out_size, void* d_ws, size_t ws_size,
                              hipStream_t stream) {
  const float* x1 = (const float*)d_in[0];
  const float* x2 = (const float*)d_in[1];
  const int* ei1 = (const int*)d_in[2];
  const int* ei2 = (const int*)d_in[3];
  const int* batch1 = (const int*)d_in[4];
  const int* batch2 = (const int*)d_in[5];
  const float* conv1W = (const float*)d_in[6];
  const float* conv1b = (const float*)d_in[7];
  const float* conv2W = (const float*)d_in[8];
  const float* conv2b = (const float*)d_in[9];
  const float* fcp1W = (const float*)d_in[10];
  const float* fcp1b = (const float*)d_in[11];
  const float* fcp2W = (const float*)d_in[12];
  const float* fcp2b = (const float*)d_in[13];
  const float* fc1W = (const float*)d_in[14];
  const float* fc1b = (const float*)d_in[15];
  const float* fc2W = (const float*)d_in[16];
  const float* fc2b = (const float*)d_in[17];
  const float* outW = (const float*)d_in[18];
  const float* outb = (const float*)d_in[19];

  int N = in_sizes[0] / 128;
  int E = in_sizes[2] / 2;

  char* ws = (char*)d_ws;
  size_t off = 0;
  auto alloc = [&](size_t bytes) -> void* {
    void* p = ws + off;
    off += (bytes + 511) & ~(size_t)511;
    return p;
  };
  float* agg = (float*)alloc((size_t)N * 128 * 4);              // 51.2 MB, reused per branch
  float* part = (float*)alloc((size_t)BGRAPH * PPARTS * 128 * 4);
  int* deg = (int*)alloc((size_t)N * 4);
  float* dinv = (float*)alloc((size_t)N * 4);
  int* start = (int*)alloc((size_t)(BGRAPH + 1) * 4);
  float* g1 = (float*)alloc((size_t)BGRAPH * 128 * 4);
  float* g2 = (float*)alloc((size_t)BGRAPH * 128 * 4);
  (void)ws_size; (void)n_in; (void)out_size;

  auto run_branch = [&](const float* x, const int* ei, const int* batch,
                        const float* convW, const float* convb, float* gout) {
    const int* src = ei;      // edge_index[0] = sources
    const int* dst = ei + E;  // edge_index[1] = destinations
    deg_init_kernel<<<(N + 255) / 256, 256, 0, stream>>>(deg, N);
    deg_count_kernel<<<(E + 255) / 256, 256, 0, stream>>>(dst, deg, E);
    dinv_kernel<<<(N + 255) / 256, 256, 0, stream>>>(deg, dinv, N);
    self_init_kernel<<<(unsigned)(((size_t)N * 32 + 255) / 256), 256, 0, stream>>>(x, dinv, agg, N);
    edge_agg_kernel<<<(unsigned)(((size_t)E * 32 + 255) / 256), 256, 0, stream>>>(src, dst, x, dinv, agg, E);
    gemm_lrelu_kernel<<<(N + GR - 1) / GR, 128, 0, stream>>>(agg, convW, convb, N);
    bounds_kernel<<<1, 256, 0, stream>>>(batch, start, N, BGRAPH);
    pool_part_kernel<<<BGRAPH * PPARTS, 128, 0, stream>>>(agg, start, part);
    pool_combine_kernel<<<BGRAPH, 128, 0, stream>>>(part, gout);
  };
  run_branch(x1, ei1, batch1, conv1W, conv1b, g1);
  run_branch(x2, ei2, batch2, conv2W, conv2b, g2);

  head_kernel<<<BGRAPH, 256, 0, stream>>>(g1, g2, fcp1W, fcp1b, fcp2W, fcp2b,
                                          fc1W, fc1b, fc2W, fc2b, outW, outb,
                                          (float*)d_out);
}

// Round 2
// 1202.957 us; speedup vs baseline: 5.0389x; 5.0389x over previous
//
#include <hip/hip_runtime.h>
#include <math.h>

#define NSLOPE 0.01f
#define BGRAPH 128
#define PPARTS 8
#define GR 32

__device__ __forceinline__ float lrelu(float v) { return v >= 0.f ? v : NSLOPE * v; }

// ---------- CSR build ----------

__global__ void cnt_zero_kernel(int* __restrict__ cnt, int n) {
  int v = blockIdx.x * blockDim.x + threadIdx.x;
  if (v < n) cnt[v] = 0;
}

__global__ void count_kernel(const int* __restrict__ dst, int* __restrict__ cnt, int ne) {
  int e = blockIdx.x * blockDim.x + threadIdx.x;
  if (e < ne) atomicAdd(&cnt[dst[e]], 1);
}

// per-256-block sums of cnt
__global__ void part_sum_kernel(const int* __restrict__ cnt, int* __restrict__ part, int n) {
  __shared__ int s[256];
  int t = threadIdx.x;
  int v = blockIdx.x * 256 + t;
  s[t] = (v < n) ? cnt[v] : 0;
  __syncthreads();
  for (int off = 128; off > 0; off >>= 1) {
    if (t < off) s[t] += s[t + off];
    __syncthreads();
  }
  if (t == 0) part[blockIdx.x] = s[0];
}

// single-block exclusive scan of part[] (nb <= 1024)
__global__ void part_scan_kernel(int* __restrict__ part, int nb) {
  __shared__ int s[1024];
  int t = threadIdx.x;
  int v = (t < nb) ? part[t] : 0;
  s[t] = v;
  __syncthreads();
  for (int off = 1; off < 1024; off <<= 1) {
    int a = (t >= off) ? s[t - off] : 0;
    __syncthreads();
    s[t] += a;
    __syncthreads();
  }
  if (t < nb) part[t] = s[t] - v;  // exclusive
}

// local scan + part offset -> rowptr, cursor; also dinv = rsqrt(cnt+1)
__global__ void rowptr_kernel(const int* __restrict__ cnt, const int* __restrict__ part,
                              int* __restrict__ rowptr, int* __restrict__ cursor,
                              float* __restrict__ dinv, int n, int ne) {
  __shared__ int s[256];
  int t = threadIdx.x;
  int v = blockIdx.x * 256 + t;
  int c = (v < n) ? cnt[v] : 0;
  s[t] = c;
  __syncthreads();
  for (int off = 1; off < 256; off <<= 1) {
    int a = (t >= off) ? s[t - off] : 0;
    __syncthreads();
    s[t] += a;
    __syncthreads();
  }
  int excl = s[t] - c + part[blockIdx.x];
  if (v < n) {
    rowptr[v] = excl;
    cursor[v] = excl;
    dinv[v] = rsqrtf((float)(c + 1));
  }
  if (v == n - 1) rowptr[n] = ne;
}

__global__ void scatter_kernel(const int* __restrict__ src, const int* __restrict__ dst,
                               int* __restrict__ cursor, int* __restrict__ csr, int ne) {
  int e = blockIdx.x * blockDim.x + threadIdx.x;
  if (e >= ne) return;
  int d = dst[e];
  int pos = atomicAdd(&cursor[d], 1);
  csr[pos] = src[e];
}

// y[v] = dinv[v] * x[v]
__global__ void y_kernel(const float* __restrict__ x, const float* __restrict__ dinv,
                         float* __restrict__ y, int n) {
  int tid = blockIdx.x * blockDim.x + threadIdx.x;
  int v = tid >> 5, l = tid & 31;
  if (v >= n) return;
  float dv = dinv[v];
  float4 xv = ((const float4*)x)[(size_t)v * 32 + l];
  float4 o;
  o.x = dv * xv.x; o.y = dv * xv.y; o.z = dv * xv.z; o.w = dv * xv.w;
  ((float4*)y)[(size_t)v * 32 + l] = o;
}

// agg[v] = dinv[v] * (y[v] + sum_{s in N(v)} y[s]); 32 lanes per node, float4/lane
__global__ void gather_kernel(const float* __restrict__ y, const int* __restrict__ csr,
                              const int* __restrict__ rowptr, const float* __restrict__ dinv,
                              float* __restrict__ agg, int n) {
  int tid = blockIdx.x * blockDim.x + threadIdx.x;
  int v = tid >> 5, l = tid & 31;
  if (v >= n) return;
  const float4* y4 = (const float4*)y;
  float4 acc = y4[(size_t)v * 32 + l];  // self term (pre-dinv scale)
  int rs = rowptr[v], re = rowptr[v + 1];
  for (int base = rs; base < re; base += 32) {
    int idx = base + l;
    int sidx = (idx < re) ? csr[idx] : 0;
    int m = min(32, re - base);
    for (int j = 0; j < m; j++) {
      int s = __shfl(sidx, j, 32);
      float4 yv = y4[(size_t)s * 32 + l];
      acc.x += yv.x; acc.y += yv.y; acc.z += yv.z; acc.w += yv.w;
    }
  }
  float dv = dinv[v];
  float4 o;
  o.x = dv * acc.x; o.y = dv * acc.y; o.z = dv * acc.z; o.w = dv * acc.w;
  ((float4*)agg)[(size_t)v * 32 + l] = o;
}

// ---------- GEMM + pooling + head (unchanged from R1) ----------

__global__ __launch_bounds__(128) void gemm_lrelu_kernel(
    float* __restrict__ A, const float* __restrict__ W,
    const float* __restrict__ bias, int n) {
  __shared__ float xs[GR * 128];
  int t = threadIdx.x;
  size_t row0 = (size_t)blockIdx.x * GR;
  if (row0 + GR <= (size_t)n) {
    const float4* A4 = (const float4*)(A + row0 * 128);
    float4* xs4 = (float4*)xs;
#pragma unroll
    for (int i = 0; i < 8; i++) xs4[t + i * 128] = A4[t + i * 128];
  } else {
    for (int idx = t; idx < GR * 128; idx += 128) {
      size_t r = row0 + (size_t)(idx >> 7);
      xs[idx] = (r < (size_t)n) ? A[r * 128 + (idx & 127)] : 0.f;
    }
  }
  __syncthreads();
  float acc[GR];
#pragma unroll
  for (int r = 0; r < GR; r++) acc[r] = 0.f;
  for (int kc = 0; kc < 4; kc++) {
    float w[32];
#pragma unroll
    for (int j = 0; j < 32; j++) w[j] = W[(kc * 32 + j) * 128 + t];
#pragma unroll
    for (int j4 = 0; j4 < 8; j4++) {
#pragma unroll
      for (int r = 0; r < GR; r++) {
        float4 xv = ((const float4*)(xs + r * 128 + kc * 32))[j4];
        acc[r] = fmaf(xv.x, w[j4 * 4 + 0], acc[r]);
        acc[r] = fmaf(xv.y, w[j4 * 4 + 1], acc[r]);
        acc[r] = fmaf(xv.z, w[j4 * 4 + 2], acc[r]);
        acc[r] = fmaf(xv.w, w[j4 * 4 + 3], acc[r]);
      }
    }
  }
  float bv = bias[t];
#pragma unroll
  for (int r = 0; r < GR; r++) {
    size_t row = row0 + r;
    if (row < (size_t)n) A[row * 128 + t] = lrelu(acc[r] + bv);
  }
}

__global__ void bounds_kernel(const int* __restrict__ batch, int* __restrict__ start,
                              int n, int nb) {
  int b = blockIdx.x * blockDim.x + threadIdx.x;
  if (b > nb) return;
  int lo = 0, hi = n;
  while (lo < hi) {
    int mid = (lo + hi) >> 1;
    if (batch[mid] < b) lo = mid + 1; else hi = mid;
  }
  start[b] = lo;
}

__global__ void pool_part_kernel(const float* __restrict__ h, const int* __restrict__ start,
                                 float* __restrict__ part) {
  int b = blockIdx.x / PPARTS, p = blockIdx.x % PPARTS;
  int t = threadIdx.x;
  int s0 = start[b], s1 = start[b + 1];
  int cnt = s1 - s0;
  int per = (cnt + PPARTS - 1) / PPARTS;
  int v0 = s0 + p * per;
  int v1 = min(s1, v0 + per);
  float m = -3.4e38f;
  for (int v = v0; v < v1; v++) m = fmaxf(m, h[(size_t)v * 128 + t]);
  part[(size_t)blockIdx.x * 128 + t] = m;
}

__global__ void pool_combine_kernel(const float* __restrict__ part, float* __restrict__ g) {
  int b = blockIdx.x, t = threadIdx.x;
  float m = -3.4e38f;
#pragma unroll
  for (int p = 0; p < PPARTS; p++) m = fmaxf(m, part[((size_t)b * PPARTS + p) * 128 + t]);
  g[(size_t)b * 128 + t] = m;
}

__global__ __launch_bounds__(256) void head_kernel(
    const float* __restrict__ g1, const float* __restrict__ g2,
    const float* __restrict__ fcp1W, const float* __restrict__ fcp1b,
    const float* __restrict__ fcp2W, const float* __restrict__ fcp2b,
    const float* __restrict__ fc1W, const float* __restrict__ fc1b,
    const float* __restrict__ fc2W, const float* __restrict__ fc2b,
    const float* __restrict__ outW, const float* __restrict__ outb,
    float* __restrict__ out) {
  __shared__ float grow[256];
  __shared__ float c[256];
  __shared__ float h1[256];
  __shared__ float h2[64];
  int b = blockIdx.x, t = threadIdx.x;
  grow[t] = (t < 128) ? g1[b * 128 + t] : g2[b * 128 + (t - 128)];
  __syncthreads();
  {
    float acc;
    if (t < 128) {
      acc = fcp1b[t];
      for (int k = 0; k < 128; k++) acc = fmaf(grow[k], fcp1W[k * 128 + t], acc);
    } else {
      int tc = t - 128;
      acc = fcp2b[tc];
      for (int k = 0; k < 128; k++) acc = fmaf(grow[128 + k], fcp2W[k * 128 + tc], acc);
    }
    c[t] = lrelu(acc);
  }
  __syncthreads();
  {
    float acc = fc1b[t];
    for (int k = 0; k < 256; k++) acc = fmaf(c[k], fc1W[k * 256 + t], acc);
    h1[t] = lrelu(acc);
  }
  __syncthreads();
  if (t < 64) {
    float acc = fc2b[t];
    for (int k = 0; k < 256; k++) acc = fmaf(h1[k], fc2W[k * 64 + t], acc);
    h2[t] = lrelu(acc);
  }
  __syncthreads();
  if (t < 64) {
    float v = h2[t] * outW[t];
    for (int off = 32; off > 0; off >>= 1) v += __shfl_down(v, off);
    if (t == 0) out[b] = 1.f / (1.f + expf(-(v + outb[0])));
  }
}

extern "C" void kernel_launch(void* const* d_in, const int* in_sizes, int n_in,
                              void* d_out, int out_size, void* d_ws, size_t ws_size,
                              hipStream_t stream) {
  const float* x1 = (const float*)d_in[0];
  const float* x2 = (const float*)d_in[1];
  const int* ei1 = (const int*)d_in[2];
  const int* ei2 = (const int*)d_in[3];
  const int* batch1 = (const int*)d_in[4];
  const int* batch2 = (const int*)d_in[5];
  const float* conv1W = (const float*)d_in[6];
  const float* conv1b = (const float*)d_in[7];
  const float* conv2W = (const float*)d_in[8];
  const float* conv2b = (const float*)d_in[9];
  const float* fcp1W = (const float*)d_in[10];
  const float* fcp1b = (const float*)d_in[11];
  const float* fcp2W = (const float*)d_in[12];
  const float* fcp2b = (const float*)d_in[13];
  const float* fc1W = (const float*)d_in[14];
  const float* fc1b = (const float*)d_in[15];
  const float* fc2W = (const float*)d_in[16];
  const float* fc2b = (const float*)d_in[17];
  const float* outW = (const float*)d_in[18];
  const float* outb = (const float*)d_in[19];

  int N = in_sizes[0] / 128;
  int E = in_sizes[2] / 2;
  int nblk = (N + 255) / 256;

  char* ws = (char*)d_ws;
  size_t off = 0;
  auto alloc = [&](size_t bytes) -> void* {
    void* p = ws + off;
    off += (bytes + 511) & ~(size_t)511;
    return p;
  };
  float* agg = (float*)alloc((size_t)N * 128 * 4);   // 51.2 MB
  float* y = (float*)alloc((size_t)N * 128 * 4);     // 51.2 MB
  int* csr = (int*)alloc((size_t)E * 4);             // 6.4 MB
  int* cnt = (int*)alloc((size_t)N * 4);
  int* rowptr = (int*)alloc((size_t)(N + 1) * 4);
  int* cursor = (int*)alloc((size_t)N * 4);
  int* part_i = (int*)alloc((size_t)1024 * 4);
  float* dinv = (float*)alloc((size_t)N * 4);
  float* part = (float*)alloc((size_t)BGRAPH * PPARTS * 128 * 4);
  int* start = (int*)alloc((size_t)(BGRAPH + 1) * 4);
  float* g1 = (float*)alloc((size_t)BGRAPH * 128 * 4);
  float* g2 = (float*)alloc((size_t)BGRAPH * 128 * 4);
  (void)ws_size; (void)n_in; (void)out_size;

  auto run_branch = [&](const float* x, const int* ei, const int* batch,
                        const float* convW, const float* convb, float* gout) {
    const int* src = ei;      // edge_index[0] = sources
    const int* dst = ei + E;  // edge_index[1] = destinations
    cnt_zero_kernel<<<nblk, 256, 0, stream>>>(cnt, N);
    count_kernel<<<(E + 255) / 256, 256, 0, stream>>>(dst, cnt, E);
    part_sum_kernel<<<nblk, 256, 0, stream>>>(cnt, part_i, N);
    part_scan_kernel<<<1, 1024, 0, stream>>>(part_i, nblk);
    rowptr_kernel<<<nblk, 256, 0, stream>>>(cnt, part_i, rowptr, cursor, dinv, N, E);
    scatter_kernel<<<(E + 255) / 256, 256, 0, stream>>>(src, dst, cursor, csr, E);
    y_kernel<<<(unsigned)(((size_t)N * 32 + 255) / 256), 256, 0, stream>>>(x, dinv, y, N);
    gather_kernel<<<(unsigned)(((size_t)N * 32 + 255) / 256), 256, 0, stream>>>(
        y, csr, rowptr, dinv, agg, N);
    gemm_lrelu_kernel<<<(N + GR - 1) / GR, 128, 0, stream>>>(agg, convW, convb, N);
    bounds_kernel<<<1, 256, 0, stream>>>(batch, start, N, BGRAPH);
    pool_part_kernel<<<BGRAPH * PPARTS, 128, 0, stream>>>(agg, start, part);
    pool_combine_kernel<<<BGRAPH, 128, 0, stream>>>(part, gout);
  };
  run_branch(x1, ei1, batch1, conv1W, conv1b, g1);
  run_branch(x2, ei2, batch2, conv2W, conv2b, g2);

  head_kernel<<<BGRAPH, 256, 0, stream>>>(g1, g2, fcp1W, fcp1b, fcp2W, fcp2b,
                                          fc1W, fc1b, fc2W, fc2b, outW, outb,
                                          (float*)d_out);
}

// Round 3
// 867.944 us; speedup vs baseline: 6.9838x; 1.3860x over previous
//
#include <hip/hip_runtime.h>
#include <math.h>

#define NSLOPE 0.01f
#define BGRAPH 128
#define PPARTS 8
#define GTILE 128
#define BK 32

__device__ __forceinline__ float lrelu(float v) { return v >= 0.f ? v : NSLOPE * v; }

// ---------- CSR build over combined node space [0, 2N) ----------

__global__ void cnt_zero_kernel(int* __restrict__ cnt, int n) {
  int v = blockIdx.x * blockDim.x + threadIdx.x;
  if (v < n) cnt[v] = 0;
}

__global__ void count_kernel(const int* __restrict__ dst1, const int* __restrict__ dst2,
                             int* __restrict__ cnt, int ne, int off) {
  int e = blockIdx.x * blockDim.x + threadIdx.x;
  if (e < ne) atomicAdd(&cnt[dst1[e]], 1);
  else if (e < 2 * ne) atomicAdd(&cnt[dst2[e - ne] + off], 1);
}

__global__ void part_sum_kernel(const int* __restrict__ cnt, int* __restrict__ part, int n) {
  __shared__ int s[256];
  int t = threadIdx.x;
  int v = blockIdx.x * 256 + t;
  s[t] = (v < n) ? cnt[v] : 0;
  __syncthreads();
  for (int off = 128; off > 0; off >>= 1) {
    if (t < off) s[t] += s[t + off];
    __syncthreads();
  }
  if (t == 0) part[blockIdx.x] = s[0];
}

__global__ void part_scan_kernel(int* __restrict__ part, int nb) {
  __shared__ int s[1024];
  int t = threadIdx.x;
  int v = (t < nb) ? part[t] : 0;
  s[t] = v;
  __syncthreads();
  for (int off = 1; off < 1024; off <<= 1) {
    int a = (t >= off) ? s[t - off] : 0;
    __syncthreads();
    s[t] += a;
    __syncthreads();
  }
  if (t < nb) part[t] = s[t] - v;  // exclusive
}

__global__ void rowptr_kernel(const int* __restrict__ cnt, const int* __restrict__ part,
                              int* __restrict__ rowptr, int* __restrict__ cursor,
                              float* __restrict__ dinv, int n, int ne) {
  __shared__ int s[256];
  int t = threadIdx.x;
  int v = blockIdx.x * 256 + t;
  int c = (v < n) ? cnt[v] : 0;
  s[t] = c;
  __syncthreads();
  for (int off = 1; off < 256; off <<= 1) {
    int a = (t >= off) ? s[t - off] : 0;
    __syncthreads();
    s[t] += a;
    __syncthreads();
  }
  int excl = s[t] - c + part[blockIdx.x];
  if (v < n) {
    rowptr[v] = excl;
    cursor[v] = excl;
    dinv[v] = rsqrtf((float)(c + 1));
  }
  if (v == n - 1) rowptr[n] = ne;
}

__global__ void scatter_kernel(const int* __restrict__ s1, const int* __restrict__ d1,
                               const int* __restrict__ s2, const int* __restrict__ d2,
                               int* __restrict__ cursor, int* __restrict__ csr,
                               int ne, int off) {
  int e = blockIdx.x * blockDim.x + threadIdx.x;
  if (e < ne) {
    int p = atomicAdd(&cursor[d1[e]], 1);
    csr[p] = s1[e];
  } else if (e < 2 * ne) {
    int i = e - ne;
    int p = atomicAdd(&cursor[d2[i] + off], 1);
    csr[p] = s2[i] + off;
  }
}

// agg[v] = dinv[v] * (dinv[v]*x[v] + sum_{s in N(v)} dinv[s]*x[s])
// 32 lanes per node, float4 per lane; x read from split buffers.
__global__ void gather_kernel(const float* __restrict__ x1, const float* __restrict__ x2,
                              const int* __restrict__ csr, const int* __restrict__ rowptr,
                              const float* __restrict__ dinv, float* __restrict__ agg,
                              int n1, int ntot) {
  int tid = blockIdx.x * blockDim.x + threadIdx.x;
  int v = tid >> 5, l = tid & 31;
  if (v >= ntot) return;
  float dv = dinv[v];
  const float* xself = (v < n1) ? (x1 + (size_t)v * 128) : (x2 + (size_t)(v - n1) * 128);
  float4 xv0 = ((const float4*)xself)[l];
  float4 acc0, acc1;
  acc0.x = dv * xv0.x; acc0.y = dv * xv0.y; acc0.z = dv * xv0.z; acc0.w = dv * xv0.w;
  acc1.x = 0.f; acc1.y = 0.f; acc1.z = 0.f; acc1.w = 0.f;
  int rs = rowptr[v], re = rowptr[v + 1];
  for (int base = rs; base < re; base += 32) {
    int idx = base + l;
    int sown = (idx < re) ? csr[idx] : 0;
    float down = (idx < re) ? dinv[sown] : 0.f;
    int m = min(32, re - base);
    for (int j = 0; j < m; j++) {
      int s = __shfl(sown, j, 32);
      float ds = __shfl(down, j, 32);
      const float* px = (s < n1) ? (x1 + (size_t)s * 128) : (x2 + (size_t)(s - n1) * 128);
      float4 xv = ((const float4*)px)[l];
      if (j & 1) {
        acc1.x = fmaf(ds, xv.x, acc1.x); acc1.y = fmaf(ds, xv.y, acc1.y);
        acc1.z = fmaf(ds, xv.z, acc1.z); acc1.w = fmaf(ds, xv.w, acc1.w);
      } else {
        acc0.x = fmaf(ds, xv.x, acc0.x); acc0.y = fmaf(ds, xv.y, acc0.y);
        acc0.z = fmaf(ds, xv.z, acc0.z); acc0.w = fmaf(ds, xv.w, acc0.w);
      }
    }
  }
  float4 o;
  o.x = dv * (acc0.x + acc1.x); o.y = dv * (acc0.y + acc1.y);
  o.z = dv * (acc0.z + acc1.z); o.w = dv * (acc0.w + acc1.w);
  ((float4*)agg)[(size_t)v * 32 + l] = o;
}

// ---------- register-tiled GEMM: C = lrelu(A@W + b), in place on agg ----------
// 128x128 block tile, 256 threads, 8x8 per thread. A staged k-major (pad 132).
__global__ __launch_bounds__(256, 3) void gemm_tiled_kernel(
    const float* A, float* C,
    const float* __restrict__ W1, const float* __restrict__ b1,
    const float* __restrict__ W2, const float* __restrict__ b2,
    int N1, int Ntot, int nbA) {
  __shared__ float xs[BK * 132];
  __shared__ float wsm[BK * 128];
  int b = blockIdx.x;
  int half = (b >= nbA) ? 1 : 0;
  const float* W = half ? W2 : W1;
  const float* bias = half ? b2 : b1;
  int base = half ? (N1 + (b - nbA) * GTILE) : b * GTILE;
  int rmax = half ? Ntot : N1;
  int t = threadIdx.x;
  int tr = t & 15, tc = t >> 4;
  int r0 = tr * 8, c0 = tc * 8;

  float acc[8][8];
#pragma unroll
  for (int i = 0; i < 8; i++)
#pragma unroll
    for (int j = 0; j < 8; j++) acc[i][j] = 0.f;

  for (int kc = 0; kc < 128; kc += BK) {
    // stage A tile transposed: xs[k][row], padded stride 132
#pragma unroll
    for (int i = 0; i < 4; i++) {
      int idx = t + i * 256;      // 0..1023
      int row = idx >> 3;         // 0..127
      int kq = idx & 7;           // float4 index along k
      int gr = base + row;
      float4 av = make_float4(0.f, 0.f, 0.f, 0.f);
      if (gr < rmax) av = ((const float4*)(A + (size_t)gr * 128 + kc))[kq];
      xs[(kq * 4 + 0) * 132 + row] = av.x;
      xs[(kq * 4 + 1) * 132 + row] = av.y;
      xs[(kq * 4 + 2) * 132 + row] = av.z;
      xs[(kq * 4 + 3) * 132 + row] = av.w;
    }
    // stage W tile row-major: wsm[k][col]
#pragma unroll
    for (int i = 0; i < 4; i++) {
      int idx = t + i * 256;      // 0..1023
      int k = idx >> 5, c4 = idx & 31;
      ((float4*)wsm)[k * 32 + c4] = ((const float4*)(W + (size_t)(kc + k) * 128))[c4];
    }
    __syncthreads();
#pragma unroll 8
    for (int k = 0; k < BK; k++) {
      float4 a0 = *(const float4*)(xs + k * 132 + r0);
      float4 a1 = *(const float4*)(xs + k * 132 + r0 + 4);
      float4 w0 = *(const float4*)(wsm + k * 128 + c0);
      float4 w1 = *(const float4*)(wsm + k * 128 + c0 + 4);
      float av[8] = {a0.x, a0.y, a0.z, a0.w, a1.x, a1.y, a1.z, a1.w};
      float wv[8] = {w0.x, w0.y, w0.z, w0.w, w1.x, w1.y, w1.z, w1.w};
#pragma unroll
      for (int i = 0; i < 8; i++)
#pragma unroll
        for (int j = 0; j < 8; j++) acc[i][j] = fmaf(av[i], wv[j], acc[i][j]);
    }
    __syncthreads();
  }

  float bv[8];
#pragma unroll
  for (int j = 0; j < 8; j++) bv[j] = bias[c0 + j];
#pragma unroll
  for (int i = 0; i < 8; i++) {
    int gr = base + r0 + i;
    if (gr < rmax) {
      float4 o0, o1;
      o0.x = lrelu(acc[i][0] + bv[0]); o0.y = lrelu(acc[i][1] + bv[1]);
      o0.z = lrelu(acc[i][2] + bv[2]); o0.w = lrelu(acc[i][3] + bv[3]);
      o1.x = lrelu(acc[i][4] + bv[4]); o1.y = lrelu(acc[i][5] + bv[5]);
      o1.z = lrelu(acc[i][6] + bv[6]); o1.w = lrelu(acc[i][7] + bv[7]);
      *(float4*)(C + (size_t)gr * 128 + c0) = o0;
      *(float4*)(C + (size_t)gr * 128 + c0 + 4) = o1;
    }
  }
}

// ---------- pooling over 256 combined graphs ----------

__global__ void bounds_kernel(const int* __restrict__ b1, const int* __restrict__ b2,
                              int* __restrict__ start, int n, int nb) {
  int b = blockIdx.x * blockDim.x + threadIdx.x;
  if (b > 2 * nb) return;
  const int* arr;
  int tgt, off;
  if (b < nb) { arr = b1; tgt = b; off = 0; }
  else { arr = b2; tgt = b - nb; off = n; }
  int lo = 0, hi = n;
  while (lo < hi) {
    int mid = (lo + hi) >> 1;
    if (arr[mid] < tgt) lo = mid + 1; else hi = mid;
  }
  start[b] = off + lo;
}

__global__ void pool_part_kernel(const float* __restrict__ h, const int* __restrict__ start,
                                 float* __restrict__ part) {
  int b = blockIdx.x / PPARTS, p = blockIdx.x % PPARTS;
  int t = threadIdx.x;
  int s0 = start[b], s1 = start[b + 1];
  int cnt = s1 - s0;
  int per = (cnt + PPARTS - 1) / PPARTS;
  int v0 = s0 + p * per;
  int v1 = min(s1, v0 + per);
  float m = -3.4e38f;
  for (int v = v0; v < v1; v++) m = fmaxf(m, h[(size_t)v * 128 + t]);
  part[(size_t)blockIdx.x * 128 + t] = m;
}

__global__ void pool_combine_kernel(const float* __restrict__ part, float* __restrict__ g) {
  int b = blockIdx.x, t = threadIdx.x;
  float m = -3.4e38f;
#pragma unroll
  for (int p = 0; p < PPARTS; p++) m = fmaxf(m, part[((size_t)b * PPARTS + p) * 128 + t]);
  g[(size_t)b * 128 + t] = m;
}

// ---------- fused head ----------

__global__ __launch_bounds__(256) void head_kernel(
    const float* __restrict__ g1, const float* __restrict__ g2,
    const float* __restrict__ fcp1W, const float* __restrict__ fcp1b,
    const float* __restrict__ fcp2W, const float* __restrict__ fcp2b,
    const float* __restrict__ fc1W, const float* __restrict__ fc1b,
    const float* __restrict__ fc2W, const float* __restrict__ fc2b,
    const float* __restrict__ outW, const float* __restrict__ outb,
    float* __restrict__ out) {
  __shared__ float grow[256];
  __shared__ float c[256];
  __shared__ float h1[256];
  __shared__ float h2[64];
  int b = blockIdx.x, t = threadIdx.x;
  grow[t] = (t < 128) ? g1[b * 128 + t] : g2[b * 128 + (t - 128)];
  __syncthreads();
  {
    float acc;
    if (t < 128) {
      acc = fcp1b[t];
      for (int k = 0; k < 128; k++) acc = fmaf(grow[k], fcp1W[k * 128 + t], acc);
    } else {
      int tc = t - 128;
      acc = fcp2b[tc];
      for (int k = 0; k < 128; k++) acc = fmaf(grow[128 + k], fcp2W[k * 128 + tc], acc);
    }
    c[t] = lrelu(acc);
  }
  __syncthreads();
  {
    float acc = fc1b[t];
    for (int k = 0; k < 256; k++) acc = fmaf(c[k], fc1W[k * 256 + t], acc);
    h1[t] = lrelu(acc);
  }
  __syncthreads();
  if (t < 64) {
    float acc = fc2b[t];
    for (int k = 0; k < 256; k++) acc = fmaf(h1[k], fc2W[k * 64 + t], acc);
    h2[t] = lrelu(acc);
  }
  __syncthreads();
  if (t < 64) {
    float v = h2[t] * outW[t];
    for (int off = 32; off > 0; off >>= 1) v += __shfl_down(v, off);
    if (t == 0) out[b] = 1.f / (1.f + expf(-(v + outb[0])));
  }
}

extern "C" void kernel_launch(void* const* d_in, const int* in_sizes, int n_in,
                              void* d_out, int out_size, void* d_ws, size_t ws_size,
                              hipStream_t stream) {
  const float* x1 = (const float*)d_in[0];
  const float* x2 = (const float*)d_in[1];
  const int* ei1 = (const int*)d_in[2];
  const int* ei2 = (const int*)d_in[3];
  const int* batch1 = (const int*)d_in[4];
  const int* batch2 = (const int*)d_in[5];
  const float* conv1W = (const float*)d_in[6];
  const float* conv1b = (const float*)d_in[7];
  const float* conv2W = (const float*)d_in[8];
  const float* conv2b = (const float*)d_in[9];
  const float* fcp1W = (const float*)d_in[10];
  const float* fcp1b = (const float*)d_in[11];
  const float* fcp2W = (const float*)d_in[12];
  const float* fcp2b = (const float*)d_in[13];
  const float* fc1W = (const float*)d_in[14];
  const float* fc1b = (const float*)d_in[15];
  const float* fc2W = (const float*)d_in[16];
  const float* fc2b = (const float*)d_in[17];
  const float* outW = (const float*)d_in[18];
  const float* outb = (const float*)d_in[19];

  int N = in_sizes[0] / 128;
  int E = in_sizes[2] / 2;
  int NT = 2 * N;           // combined node space
  int nblk2 = (NT + 255) / 256;

  char* ws = (char*)d_ws;
  size_t off = 0;
  auto alloc = [&](size_t bytes) -> void* {
    void* p = ws + off;
    off += (bytes + 511) & ~(size_t)511;
    return p;
  };
  float* agg = (float*)alloc((size_t)NT * 128 * 4);   // 102.4 MB
  int* csr = (int*)alloc((size_t)2 * E * 4);          // 12.8 MB
  int* cnt = (int*)alloc((size_t)NT * 4);
  int* rowptr = (int*)alloc((size_t)(NT + 1) * 4);
  int* cursor = (int*)alloc((size_t)NT * 4);
  int* part_i = (int*)alloc((size_t)1024 * 4);
  float* dinv = (float*)alloc((size_t)NT * 4);
  float* part = (float*)alloc((size_t)2 * BGRAPH * PPARTS * 128 * 4);
  int* start = (int*)alloc((size_t)(2 * BGRAPH + 1) * 4);
  float* g = (float*)alloc((size_t)2 * BGRAPH * 128 * 4);
  (void)ws_size; (void)n_in; (void)out_size;

  const int* src1 = ei1, *dst1 = ei1 + E;
  const int* src2 = ei2, *dst2 = ei2 + E;

  cnt_zero_kernel<<<nblk2, 256, 0, stream>>>(cnt, NT);
  count_kernel<<<(2 * E + 255) / 256, 256, 0, stream>>>(dst1, dst2, cnt, E, N);
  part_sum_kernel<<<nblk2, 256, 0, stream>>>(cnt, part_i, NT);
  part_scan_kernel<<<1, 1024, 0, stream>>>(part_i, nblk2);
  rowptr_kernel<<<nblk2, 256, 0, stream>>>(cnt, part_i, rowptr, cursor, dinv, NT, 2 * E);
  scatter_kernel<<<(2 * E + 255) / 256, 256, 0, stream>>>(src1, dst1, src2, dst2,
                                                          cursor, csr, E, N);
  gather_kernel<<<(unsigned)(((size_t)NT * 32 + 255) / 256), 256, 0, stream>>>(
      x1, x2, csr, rowptr, dinv, agg, N, NT);
  int nbA = (N + GTILE - 1) / GTILE;
  gemm_tiled_kernel<<<2 * nbA, 256, 0, stream>>>(agg, agg, conv1W, conv1b,
                                                 conv2W, conv2b, N, NT, nbA);
  bounds_kernel<<<2, 256, 0, stream>>>(batch1, batch2, start, N, BGRAPH);
  pool_part_kernel<<<2 * BGRAPH * PPARTS, 128, 0, stream>>>(agg, start, part);
  pool_combine_kernel<<<2 * BGRAPH, 128, 0, stream>>>(part, g);

  head_kernel<<<BGRAPH, 256, 0, stream>>>(g, g + (size_t)BGRAPH * 128,
                                          fcp1W, fcp1b, fcp2W, fcp2b,
                                          fc1W, fc1b, fc2W, fc2b, outW, outb,
                                          (float*)d_out);
}